// Round 13
// baseline (474.191 us; speedup 1.0000x reference)
//
#include <hip/hip_runtime.h>
#include <math.h>

// Problem constants
#define B_    256
#define N_    128
#define F_    133
#define H_    8
#define ND_   64     // NHID
#define HID_  300
#define FPD_  1489
#define FP2_  512
#define ALPHA_ 0.2f
#define NEG_  -9.0e15f

typedef __bf16 bf16x8 __attribute__((ext_vector_type(8)));
typedef __bf16 bf16x4 __attribute__((ext_vector_type(4)));
typedef float f32x4 __attribute__((ext_vector_type(4)));

__device__ __forceinline__ float wred_sum(float v) {
#pragma unroll
  for (int m = 32; m >= 1; m >>= 1) v += __shfl_xor(v, m, 64);
  return v;
}
__device__ __forceinline__ float wred_max(float v) {
#pragma unroll
  for (int m = 32; m >= 1; m >>= 1) v = fmaxf(v, __shfl_xor(v, m, 64));
  return v;
}
__device__ __forceinline__ float lrelu(float x) { return x > 0.f ? x : ALPHA_ * x; }
__device__ __forceinline__ float eluf(float x)  { return x > 0.f ? x : expf(x) - 1.f; }
// 16B load at 4B alignment (safe form)
__device__ __forceinline__ float4 ld4u(const float* p) {
  float4 v;
  __builtin_memcpy(&v, p, 16);
  return v;
}

// Transpose + split-bf16 a KxN fp32 matrix into [N][K] hi/lo bf16 planes.
__global__ void k_wsplit(const float* __restrict__ Wm, __bf16* __restrict__ th,
                         __bf16* __restrict__ tl, int K, int Ncol) {
  const int idx = blockIdx.x * 256 + threadIdx.x;
  if (idx >= K * Ncol) return;
  const int k = idx / Ncol, c = idx - k * Ncol;
  float v = Wm[idx];
  __bf16 hv = (__bf16)v;
  th[(size_t)c * K + k] = hv;
  tl[(size_t)c * K + k] = (__bf16)(v - (float)hv);
}

// K1 (MFMA): Wh[b,h,n,d] = sum_f A[b,n,f] * W[h,f,d] via split-bf16 MFMA.
// Block = 128 rows x 1 head, 512 thr / 8 waves. s/d epilogue from acc regs.
__global__ __launch_bounds__(512) void k1_mfma(
    const float* __restrict__ A, const float* __restrict__ W,
    const float* __restrict__ ahp, float* __restrict__ Wh,
    float* __restrict__ sb, float* __restrict__ db) {
  __shared__ __align__(16) __bf16 wth[64 * 168];
  __shared__ __align__(16) __bf16 wtl[64 * 168];
  const int tid = threadIdx.x;
  const int lane = tid & 63;
  const int wv = tid >> 6;
  const int h = blockIdx.y;
  const int m0 = blockIdx.x * 128;

  {
    const float* Wg = W + (size_t)h * F_ * ND_;
    const int d = tid >> 3;
    const int kq = tid & 7;
    for (int k = kq; k < 168; k += 8) {
      float v = (k < F_) ? Wg[k * ND_ + d] : 0.f;
      __bf16 hv = (__bf16)v;
      wth[d * 168 + k] = hv;
      wtl[d * 168 + k] = (__bf16)(v - (float)hv);
    }
  }
  __syncthreads();

  const int mrow = m0 + wv * 16 + (lane & 15);
  const float* Ap = A + (size_t)mrow * F_;
  f32x4 acc[4];
#pragma unroll
  for (int t = 0; t < 4; ++t) acc[t] = f32x4{0.f, 0.f, 0.f, 0.f};

#pragma unroll
  for (int ks = 0; ks < 5; ++ks) {
    const int kb = ks * 32 + (lane >> 4) * 8;
    float av[8];
    if (ks < 4) {
      float4 a0 = ld4u(Ap + kb);
      float4 a1 = ld4u(Ap + kb + 4);
      av[0] = a0.x; av[1] = a0.y; av[2] = a0.z; av[3] = a0.w;
      av[4] = a1.x; av[5] = a1.y; av[6] = a1.z; av[7] = a1.w;
    } else {
#pragma unroll
      for (int j = 0; j < 8; ++j)
        av[j] = (kb + j < F_) ? Ap[kb + j] : 0.f;
    }
    bf16x8 ah8, al8;
#pragma unroll
    for (int j = 0; j < 8; ++j) {
      float v = av[j];
      __bf16 hv = (__bf16)v;
      ah8[j] = hv;
      al8[j] = (__bf16)(v - (float)hv);
    }
#pragma unroll
    for (int ct = 0; ct < 4; ++ct) {
      const int d = ct * 16 + (lane & 15);
      bf16x8 bh8 = *reinterpret_cast<const bf16x8*>(&wth[d * 168 + kb]);
      bf16x8 bl8 = *reinterpret_cast<const bf16x8*>(&wtl[d * 168 + kb]);
      acc[ct] = __builtin_amdgcn_mfma_f32_16x16x32_bf16(al8, bh8, acc[ct], 0, 0, 0);
      acc[ct] = __builtin_amdgcn_mfma_f32_16x16x32_bf16(ah8, bl8, acc[ct], 0, 0, 0);
      acc[ct] = __builtin_amdgcn_mfma_f32_16x16x32_bf16(ah8, bh8, acc[ct], 0, 0, 0);
    }
  }

  const size_t bh = (size_t)blockIdx.x * H_ + h;
  float* Whb = Wh + bh * N_ * ND_;
  const int n0 = wv * 16 + (lane >> 4) * 4;
#pragma unroll
  for (int ct = 0; ct < 4; ++ct) {
    const int d = ct * 16 + (lane & 15);
#pragma unroll
    for (int r = 0; r < 4; ++r)
      Whb[(size_t)(n0 + r) * ND_ + d] = acc[ct][r];
  }

  {
    float a1v[4], a2v[4];
#pragma unroll
    for (int ct = 0; ct < 4; ++ct) {
      a1v[ct] = ahp[h * 2 * ND_ + ct * 16 + (lane & 15)];
      a2v[ct] = ahp[h * 2 * ND_ + ND_ + ct * 16 + (lane & 15)];
    }
#pragma unroll
    for (int r = 0; r < 4; ++r) {
      float sv = 0.f, dv = 0.f;
#pragma unroll
      for (int ct = 0; ct < 4; ++ct) {
        sv = fmaf(acc[ct][r], a1v[ct], sv);
        dv = fmaf(acc[ct][r], a2v[ct], dv);
      }
#pragma unroll
      for (int m = 1; m <= 8; m <<= 1) {
        sv += __shfl_xor(sv, m, 64);
        dv += __shfl_xor(dv, m, 64);
      }
      if ((lane & 15) == 0) {
        sb[bh * N_ + n0 + r] = sv;
        db[bh * N_ + n0 + r] = dv;
      }
    }
  }
}

// K2: masked softmax + h = elu(attn @ Wh) via MFMA. Barrier-free.
// Epilogue writes hb as split-bf16 pair (A-operand of gemm512_s).
__global__ __launch_bounds__(512) void k2_attn1(
    const float* __restrict__ Wh, const float* __restrict__ sb,
    const float* __restrict__ db, const int* __restrict__ adj,
    __bf16* __restrict__ hbh, __bf16* __restrict__ hbl) {
  __shared__ __align__(16) __bf16 ph[128 * 136];
  __shared__ __align__(16) __bf16 pl[128 * 136];
  const int tid = threadIdx.x;
  const int lane = tid & 63;
  const int w = tid >> 6;
  const int bh = blockIdx.x;
  const int b = bh >> 3, h = bh & 7;
  const int i0 = w * 16;

  {
    const float dv0 = db[(size_t)bh * N_ + lane];
    const float dv1 = db[(size_t)bh * N_ + 64 + lane];
    int a0v[16], a1v[16];
#pragma unroll
    for (int r = 0; r < 16; ++r) {
      const int* arow = adj + ((size_t)b * N_ + i0 + r) * N_;
      a0v[r] = arow[lane];
      a1v[r] = arow[64 + lane];
    }
#pragma unroll
    for (int r = 0; r < 16; ++r) {
      const int i = i0 + r;
      const float sv = sb[(size_t)bh * N_ + i];
      float e0 = a0v[r] > 0 ? lrelu(sv + dv0) : NEG_;
      float e1 = a1v[r] > 0 ? lrelu(sv + dv1) : NEG_;
      float mx = wred_max(fmaxf(e0, e1));
      float x0 = expf(e0 - mx), x1 = expf(e1 - mx);
      float inv = 1.f / wred_sum(x0 + x1);
      float p0 = x0 * inv, p1 = x1 * inv;
      __bf16 h0 = (__bf16)p0, h1 = (__bf16)p1;
      ph[i * 136 + lane] = h0;
      ph[i * 136 + 64 + lane] = h1;
      pl[i * 136 + lane] = (__bf16)(p0 - (float)h0);
      pl[i * 136 + 64 + lane] = (__bf16)(p1 - (float)h1);
    }
  }
  // No __syncthreads: wave reads only rows it wrote.

  {
    const int arow = i0 + (lane & 15);
    const float* Whp = Wh + (size_t)bh * N_ * ND_;
    f32x4 acc[4];
#pragma unroll
    for (int t = 0; t < 4; ++t) acc[t] = f32x4{0.f, 0.f, 0.f, 0.f};
#pragma unroll
    for (int ks = 0; ks < 4; ++ks) {
      const int kb = ks * 32 + (lane >> 4) * 8;
      bf16x8 ah8 = *reinterpret_cast<const bf16x8*>(&ph[arow * 136 + kb]);
      bf16x8 al8 = *reinterpret_cast<const bf16x8*>(&pl[arow * 136 + kb]);
#pragma unroll
      for (int ct = 0; ct < 4; ++ct) {
        const int d = ct * 16 + (lane & 15);
        const float* Bc = Whp + (size_t)kb * ND_ + d;
        float bv[8];
#pragma unroll
        for (int i = 0; i < 8; ++i) bv[i] = Bc[(size_t)i * ND_];
        bf16x8 bh8, bl8;
#pragma unroll
        for (int j = 0; j < 8; ++j) {
          float v = bv[j];
          __bf16 hv = (__bf16)v;
          bh8[j] = hv;
          bl8[j] = (__bf16)(v - (float)hv);
        }
        acc[ct] = __builtin_amdgcn_mfma_f32_16x16x32_bf16(al8, bh8, acc[ct], 0, 0, 0);
        acc[ct] = __builtin_amdgcn_mfma_f32_16x16x32_bf16(ah8, bl8, acc[ct], 0, 0, 0);
        acc[ct] = __builtin_amdgcn_mfma_f32_16x16x32_bf16(ah8, bh8, acc[ct], 0, 0, 0);
      }
    }
    const int orow0 = i0 + (lane >> 4) * 4;
#pragma unroll
    for (int ct = 0; ct < 4; ++ct) {
      const int d = ct * 16 + (lane & 15);
#pragma unroll
      for (int r = 0; r < 4; ++r) {
        const int i = orow0 + r;
        float ev = eluf(acc[ct][r]);
        __bf16 hv = (__bf16)ev;
        const size_t idx = ((size_t)b * N_ + i) * (H_ * ND_) + h * ND_ + d;
        hbh[idx] = hv;
        hbl[idx] = (__bf16)(ev - (float)hv);
      }
    }
  }
}

// GEMM512: Wh2 = hb @ Wout via pre-split bf16 operands (MFMA).
// A: hbh/hbl [32768][512]; B: WoutT hi/lo [300][512] (transposed, contiguous
// k). Epilogue: Wh2 written as TRANSPOSED split pair [b][300][128] (B-ready
// for gemm128) + fused s2/d2 projections (k4 eliminated).
// Block 256 thr = 4 waves (2 row-strips x 2 col-halves), BM=32, grid 1024.
__global__ __launch_bounds__(256) void gemm512_s(
    const __bf16* __restrict__ Ah, const __bf16* __restrict__ Al,
    const __bf16* __restrict__ BTh, const __bf16* __restrict__ BTl,
    const float* __restrict__ ao,
    __bf16* __restrict__ CTh, __bf16* __restrict__ CTl,
    float* __restrict__ s2, float* __restrict__ d2) {
  __shared__ float sdp[2][2][16][2];
  const int tid = threadIdx.x;
  const int lane = tid & 63;
  const int wv = tid >> 6;
  const int rs = wv >> 1, ch = wv & 1;
  const int m0 = blockIdx.x * 32 + rs * 16;
  const int ct0 = ch * 10;
  const int nct = ch ? 9 : 10;
  const int row = m0 + (lane & 15);
  f32x4 acc[10];
#pragma unroll
  for (int t = 0; t < 10; ++t) acc[t] = f32x4{0.f, 0.f, 0.f, 0.f};

  for (int ks = 0; ks < 16; ++ks) {
    const int kb = ks * 32 + (lane >> 4) * 8;
    bf16x8 ah8 = *reinterpret_cast<const bf16x8*>(Ah + (size_t)row * 512 + kb);
    bf16x8 al8 = *reinterpret_cast<const bf16x8*>(Al + (size_t)row * 512 + kb);
#pragma unroll
    for (int t = 0; t < 10; ++t) {
      if (t < nct) {
        const int col = (ct0 + t) * 16 + (lane & 15);
        bf16x8 bh8 = bf16x8{0,0,0,0,0,0,0,0}, bl8 = bf16x8{0,0,0,0,0,0,0,0};
        if (col < HID_) {
          bh8 = *reinterpret_cast<const bf16x8*>(BTh + (size_t)col * 512 + kb);
          bl8 = *reinterpret_cast<const bf16x8*>(BTl + (size_t)col * 512 + kb);
        }
        acc[t] = __builtin_amdgcn_mfma_f32_16x16x32_bf16(al8, bh8, acc[t], 0, 0, 0);
        acc[t] = __builtin_amdgcn_mfma_f32_16x16x32_bf16(ah8, bl8, acc[t], 0, 0, 0);
        acc[t] = __builtin_amdgcn_mfma_f32_16x16x32_bf16(ah8, bh8, acc[t], 0, 0, 0);
      }
    }
  }

  // Wh2T store (split pair, [b][col][k]); 4 consecutive k per lane-tile.
  const int b = blockIdx.x >> 2;
  const int kloc0 = (m0 & 127) + (lane >> 4) * 4;
#pragma unroll
  for (int t = 0; t < 10; ++t) {
    if (t < nct) {
      const int col = (ct0 + t) * 16 + (lane & 15);
      if (col < HID_) {
        bf16x4 hv4, lv4;
#pragma unroll
        for (int r = 0; r < 4; ++r) {
          float v = acc[t][r];
          __bf16 hv = (__bf16)v;
          hv4[r] = hv;
          lv4[r] = (__bf16)(v - (float)hv);
        }
        const size_t off = ((size_t)b * HID_ + col) * 128 + kloc0;
        *reinterpret_cast<bf16x4*>(CTh + off) = hv4;
        *reinterpret_cast<bf16x4*>(CTl + off) = lv4;
      }
    }
  }

  // Fused s2/d2 projections.
  {
    float aov[10], aod[10];
#pragma unroll
    for (int t = 0; t < 10; ++t) {
      const int col = (ct0 + t) * 16 + (lane & 15);
      const bool cv = (t < nct) && (col < HID_);
      aov[t] = cv ? ao[col] : 0.f;
      aod[t] = cv ? ao[HID_ + col] : 0.f;
    }
#pragma unroll
    for (int r = 0; r < 4; ++r) {
      float sv = 0.f, dv = 0.f;
#pragma unroll
      for (int t = 0; t < 10; ++t) {
        sv = fmaf(acc[t][r], aov[t], sv);
        dv = fmaf(acc[t][r], aod[t], dv);
      }
#pragma unroll
      for (int m = 1; m <= 8; m <<= 1) {
        sv += __shfl_xor(sv, m, 64);
        dv += __shfl_xor(dv, m, 64);
      }
      if ((lane & 15) == 0) {
        const int rl = (lane >> 4) * 4 + r;
        sdp[rs][ch][rl][0] = sv;
        sdp[rs][ch][rl][1] = dv;
      }
    }
  }
  __syncthreads();
  if (tid < 32) {
    const int rs2 = tid >> 4, rl = tid & 15;
    const int row2 = blockIdx.x * 32 + rs2 * 16 + rl;
    s2[row2] = sdp[rs2][0][rl][0] + sdp[rs2][1][rl][0];
    d2[row2] = sdp[rs2][0][rl][1] + sdp[rs2][1][rl][1];
  }
}

// GEMM128: ob = elu(p2 @ Wh2) via pre-split operands. A: p2h/p2l [32768][128];
// B: Wh2T pair [b][300][128] (batched). Writes ob fp32 [32768][300].
__global__ __launch_bounds__(256) void gemm128_s(
    const __bf16* __restrict__ Ah, const __bf16* __restrict__ Al,
    const __bf16* __restrict__ BTh, const __bf16* __restrict__ BTl,
    float* __restrict__ C) {
  const int tid = threadIdx.x;
  const int lane = tid & 63;
  const int wv = tid >> 6;
  const int rs = wv >> 1, ch = wv & 1;
  const int m0 = blockIdx.x * 32 + rs * 16;
  const int ct0 = ch * 10;
  const int nct = ch ? 9 : 10;
  const int row = m0 + (lane & 15);
  const int b = blockIdx.x >> 2;
  const __bf16* Bh = BTh + (size_t)b * HID_ * 128;
  const __bf16* Bl = BTl + (size_t)b * HID_ * 128;
  f32x4 acc[10];
#pragma unroll
  for (int t = 0; t < 10; ++t) acc[t] = f32x4{0.f, 0.f, 0.f, 0.f};

#pragma unroll
  for (int ks = 0; ks < 4; ++ks) {
    const int kb = ks * 32 + (lane >> 4) * 8;
    bf16x8 ah8 = *reinterpret_cast<const bf16x8*>(Ah + (size_t)row * 128 + kb);
    bf16x8 al8 = *reinterpret_cast<const bf16x8*>(Al + (size_t)row * 128 + kb);
#pragma unroll
    for (int t = 0; t < 10; ++t) {
      if (t < nct) {
        const int col = (ct0 + t) * 16 + (lane & 15);
        bf16x8 bh8 = bf16x8{0,0,0,0,0,0,0,0}, bl8 = bf16x8{0,0,0,0,0,0,0,0};
        if (col < HID_) {
          bh8 = *reinterpret_cast<const bf16x8*>(Bh + (size_t)col * 128 + kb);
          bl8 = *reinterpret_cast<const bf16x8*>(Bl + (size_t)col * 128 + kb);
        }
        acc[t] = __builtin_amdgcn_mfma_f32_16x16x32_bf16(al8, bh8, acc[t], 0, 0, 0);
        acc[t] = __builtin_amdgcn_mfma_f32_16x16x32_bf16(ah8, bl8, acc[t], 0, 0, 0);
        acc[t] = __builtin_amdgcn_mfma_f32_16x16x32_bf16(ah8, bh8, acc[t], 0, 0, 0);
      }
    }
  }

  const int orow = m0 + (lane >> 4) * 4;
#pragma unroll
  for (int t = 0; t < 10; ++t) {
    if (t < nct) {
      const int col = (ct0 + t) * 16 + (lane & 15);
      if (col < HID_) {
#pragma unroll
        for (int r = 0; r < 4; ++r)
          C[(size_t)(orow + r) * HID_ + col] = eluf(acc[t][r]);
      }
    }
  }
}

// Split-K partial GEMM for small-M matmuls: grid (M/ROWS, KSPLIT).
template <int ROWS, int KSPLIT>
__global__ void gemm_skp(const float* __restrict__ A, const float* __restrict__ Bm,
                         float* __restrict__ P, int M, int K, int N) {
  const int c = threadIdx.x;
  const int r0 = blockIdx.x * ROWS;
  const int ks = blockIdx.y;
  if (c >= N) return;
  const int kchunk = (K + KSPLIT - 1) / KSPLIT;
  const int k0 = ks * kchunk;
  const int k1 = (k0 + kchunk < K) ? (k0 + kchunk) : K;
  float acc[ROWS];
#pragma unroll
  for (int r = 0; r < ROWS; ++r) acc[r] = 0.f;
  int k = k0;
  for (; k + 3 < k1; k += 4) {
    const float b0 = Bm[(size_t)(k + 0) * N + c];
    const float b1 = Bm[(size_t)(k + 1) * N + c];
    const float b2 = Bm[(size_t)(k + 2) * N + c];
    const float b3 = Bm[(size_t)(k + 3) * N + c];
#pragma unroll
    for (int r = 0; r < ROWS; ++r) {
      float4 a = ld4u(A + (size_t)(r0 + r) * K + k);
      acc[r] = fmaf(a.x, b0, acc[r]);
      acc[r] = fmaf(a.y, b1, acc[r]);
      acc[r] = fmaf(a.z, b2, acc[r]);
      acc[r] = fmaf(a.w, b3, acc[r]);
    }
  }
  for (; k < k1; ++k) {
    const float bv = Bm[(size_t)k * N + c];
#pragma unroll
    for (int r = 0; r < ROWS; ++r)
      acc[r] = fmaf(A[(size_t)(r0 + r) * K + k], bv, acc[r]);
  }
#pragma unroll
  for (int r = 0; r < ROWS; ++r)
    P[((size_t)ks * M + r0 + r) * N + c] = acc[r];
}

// Reduce split-K partials + bias + act. act: 0 none, 1 relu.
template <int KSPLIT>
__global__ void k_red(const float* __restrict__ P, const float* __restrict__ bias,
                      float* __restrict__ C, int M, int N, int ldc, int act) {
  const int idx = blockIdx.x * 256 + threadIdx.x;
  if (idx >= M * N) return;
  const int m = idx / N, c = idx - m * N;
  float v = 0.f;
#pragma unroll
  for (int p = 0; p < KSPLIT; ++p) v += P[(size_t)p * M * N + idx];
  if (bias) v += bias[c];
  if (act == 1) v = fmaxf(v, 0.f);
  C[(size_t)m * ldc + c] = v;
}

// K5: attn2 probabilities p2 (split-bf16 pair). One wave per row i.
__global__ __launch_bounds__(256) void k5_p2(
    const float* __restrict__ s2, const float* __restrict__ d2,
    const int* __restrict__ adj, __bf16* __restrict__ p2h,
    __bf16* __restrict__ p2l) {
  const int lane = threadIdx.x & 63;
  const int row = blockIdx.x * 4 + (threadIdx.x >> 6);  // b*N+i
  const int b = row >> 7;
  float sv = s2[row];
  const float* drow = d2 + (size_t)b * N_;
  const int* arow = adj + (size_t)row * N_;
  float dv0 = drow[lane], dv1 = drow[64 + lane];
  int a0 = arow[lane], a1i = arow[64 + lane];
  float e0 = a0 > 0 ? lrelu(sv + dv0) : NEG_;
  float e1 = a1i > 0 ? lrelu(sv + dv1) : NEG_;
  float mx = wred_max(fmaxf(e0, e1));
  float x0 = expf(e0 - mx), x1 = expf(e1 - mx);
  float inv = 1.f / wred_sum(x0 + x1);
  float p0 = x0 * inv, p1 = x1 * inv;
  __bf16 h0 = (__bf16)p0, h1 = (__bf16)p1;
  p2h[(size_t)row * N_ + lane] = h0;
  p2l[(size_t)row * N_ + lane] = (__bf16)(p0 - (float)h0);
  p2h[(size_t)row * N_ + 64 + lane] = h1;
  p2l[(size_t)row * N_ + 64 + lane] = (__bf16)(p1 - (float)h1);
}

// K7: per-row max and log-sum-exp over 300 cols. One wave per row.
__global__ __launch_bounds__(256) void k7_lse(
    const float* __restrict__ ob, float* __restrict__ mx, float* __restrict__ ls) {
  const int lane = threadIdx.x & 63;
  const int row = blockIdx.x * 4 + (threadIdx.x >> 6);
  const float* orow = ob + (size_t)row * HID_;
  float v[5], m = -1e30f;
#pragma unroll
  for (int q = 0; q < 5; ++q) {
    int c = lane + q * 64;
    v[q] = (c < HID_) ? orow[c] : -1e30f;
    m = fmaxf(m, v[q]);
  }
  m = wred_max(m);
  float s = 0.f;
#pragma unroll
  for (int q = 0; q < 5; ++q) {
    int c = lane + q * 64;
    if (c < HID_) s += expf(v[q] - m);
  }
  s = wred_sum(s);
  if (lane == 0) { mx[row] = m; ls[row] = logf(s); }
}

// K8: gat_out[b,c] = mean_i (ob[b,i,c] - mx - ls). grid 256, block 320.
__global__ void k8_mean(const float* __restrict__ ob, const float* __restrict__ mx,
                        const float* __restrict__ ls, float* __restrict__ gat) {
  const int c = threadIdx.x;
  const int b = blockIdx.x;
  if (c >= HID_) return;
  float acc = 0.f;
  for (int i = 0; i < N_; ++i) {
    int row = b * N_ + i;
    acc += ob[(size_t)row * HID_ + c] - mx[row] - ls[row];
  }
  gat[(size_t)b * HID_ + c] = acc * (1.f / N_);
}

// out[b] = sigmoid(y[b,:] @ ffn_w2 + b2). One wave per row.
__global__ __launch_bounds__(256) void k_final(
    const float* __restrict__ y, const float* __restrict__ w2,
    const float* __restrict__ b2, float* __restrict__ out) {
  const int lane = threadIdx.x & 63;
  const int b = blockIdx.x * 4 + (threadIdx.x >> 6);
  float acc = 0.f;
  for (int c = lane; c < HID_; c += 64)
    acc = fmaf(y[(size_t)b * HID_ + c], w2[c], acc);
  acc = wred_sum(acc);
  if (lane == 0) out[b] = 1.f / (1.f + expf(-(acc + b2[0])));
}

extern "C" void kernel_launch(void* const* d_in, const int* in_sizes, int n_in,
                              void* d_out, int out_size, void* d_ws, size_t ws_size,
                              hipStream_t stream) {
  const float* atom  = (const float*)d_in[0];
  const float* fp    = (const float*)d_in[1];
  const float* Whead = (const float*)d_in[2];
  const float* ah    = (const float*)d_in[3];
  const float* Wout  = (const float*)d_in[4];
  const float* aout  = (const float*)d_in[5];
  const float* fc1w  = (const float*)d_in[6];
  const float* fc1b  = (const float*)d_in[7];
  const float* fc2w  = (const float*)d_in[8];
  const float* fc2b  = (const float*)d_in[9];
  const float* fgw   = (const float*)d_in[10];
  const float* fgb   = (const float*)d_in[11];
  const float* ffw   = (const float*)d_in[12];
  const float* ffb   = (const float*)d_in[13];
  const float* w1    = (const float*)d_in[14];
  const float* b1    = (const float*)d_in[15];
  const float* w2    = (const float*)d_in[16];
  const float* b2    = (const float*)d_in[17];
  const int*   adj   = (const int*)d_in[18];
  float* out = (float*)d_out;

  float* ws = (float*)d_ws;
  // Aliased layout (peak ~138.9 MB, unchanged):
  float* Wh     = ws;                      // 16,777,216 f  [k1 w, k2 r]
  __bf16* Wh2Th = (__bf16*)ws;             // 9.83M u16     [gemm512 w, gemm128 r]
  __bf16* Wh2Tl = (__bf16*)(ws + 4915200);
  float* pbuf   = ws;                      // [FPN + head phases only]
  __bf16* p2h   = (__bf16*)(ws + 9830400); // 4.19M u16 each
  __bf16* p2l   = (__bf16*)(ws + 11927552);
  float* sb     = ws + 16777216;
  float* db     = ws + 17039360;
  __bf16* hbh   = (__bf16*)(ws + 17301504); // 16.7M u16 each
  __bf16* hbl   = (__bf16*)(ws + 25690112);
  float* ob     = ws + 17301504;           // [gemm128 w; hb pair dead]
  float* s2     = ws + 34078720;
  float* d2     = s2 + 32768;
  float* mxb    = d2 + 32768;
  float* lsb    = mxb + 32768;
  float* gat    = lsb + 32768;             //  76,800
  float* fpn1   = gat + 76800;             // 131,072
  float* fpn2   = fpn1 + 131072;           //  76,800
  float* xcat   = fpn2 + 76800;            // 153,600
  float* yb     = xcat + 153600;           //  76,800
  __bf16* WoutTh = (__bf16*)xcat;          // WoutT pair borrows xcat slot
  __bf16* WoutTl = (__bf16*)(xcat + 76800);//  (dead before head phase)

  // Wout -> transposed split pair (B-operand of gemm512_s).
  k_wsplit<<<600, 256, 0, stream>>>(Wout, WoutTh, WoutTl, FP2_, HID_);

  // FPN branch (pbuf aliases Wh region; runs before k1)
  gemm_skp<4, 8><<<dim3(64, 8), 512, 0, stream>>>(fp, fc1w, pbuf, B_, FPD_, FP2_);
  k_red<8><<<512, 256, 0, stream>>>(pbuf, fc1b, fpn1, B_, FP2_, FP2_, 1);
  gemm_skp<4, 4><<<dim3(64, 4), 320, 0, stream>>>(fpn1, fc2w, pbuf, B_, FP2_, HID_);
  k_red<4><<<300, 256, 0, stream>>>(pbuf, fc2b, fpn2, B_, HID_, HID_, 0);

  // GAT stage 1
  k1_mfma<<<dim3(256, 8), 512, 0, stream>>>(atom, Whead, ah, Wh, sb, db);
  k2_attn1<<<2048, 512, 0, stream>>>(Wh, sb, db, adj, hbh, hbl);

  // Wh2 = hb @ Wout (+fused s2/d2), output transposed split pair.
  gemm512_s<<<1024, 256, 0, stream>>>(hbh, hbl, WoutTh, WoutTl, aout,
                                      Wh2Th, Wh2Tl, s2, d2);

  // GAT stage 2
  k5_p2<<<8192, 256, 0, stream>>>(s2, d2, adj, p2h, p2l);
  gemm128_s<<<1024, 256, 0, stream>>>(p2h, p2l, Wh2Th, Wh2Tl, ob);
  k7_lse<<<8192, 256, 0, stream>>>(ob, mxb, lsb);
  k8_mean<<<256, 320, 0, stream>>>(ob, mxb, lsb, gat);

  // Head (low ws region dead -> pbuf reuse safe; xcat written after WoutT dead)
  gemm_skp<4, 4><<<dim3(64, 4), 320, 0, stream>>>(gat, fgw, pbuf, B_, HID_, HID_);
  k_red<4><<<300, 256, 0, stream>>>(pbuf, fgb, xcat, B_, HID_, 2 * HID_, 1);
  gemm_skp<4, 4><<<dim3(64, 4), 320, 0, stream>>>(fpn2, ffw, pbuf, B_, HID_, HID_);
  k_red<4><<<300, 256, 0, stream>>>(pbuf, ffb, xcat + 300, B_, HID_, 2 * HID_, 1);
  gemm_skp<4, 4><<<dim3(64, 4), 320, 0, stream>>>(xcat, w1, pbuf, B_, 2 * HID_, HID_);
  k_red<4><<<300, 256, 0, stream>>>(pbuf, b1, yb, B_, HID_, HID_, 1);
  k_final<<<64, 256, 0, stream>>>(yb, w2, b2, out);
}

// Round 15
// 434.063 us; speedup vs baseline: 1.0924x; 1.0924x over previous
//
#include <hip/hip_runtime.h>
#include <math.h>

// Problem constants
#define B_    256
#define N_    128
#define F_    133
#define H_    8
#define ND_   64     // NHID
#define HID_  300
#define FPD_  1489
#define FP2_  512
#define ALPHA_ 0.2f
#define NEG_  -9.0e15f

typedef __bf16 bf16x8 __attribute__((ext_vector_type(8)));
typedef __bf16 bf16x4 __attribute__((ext_vector_type(4)));
typedef float f32x4 __attribute__((ext_vector_type(4)));

__device__ __forceinline__ float wred_sum(float v) {
#pragma unroll
  for (int m = 32; m >= 1; m >>= 1) v += __shfl_xor(v, m, 64);
  return v;
}
__device__ __forceinline__ float wred_max(float v) {
#pragma unroll
  for (int m = 32; m >= 1; m >>= 1) v = fmaxf(v, __shfl_xor(v, m, 64));
  return v;
}
__device__ __forceinline__ float lrelu(float x) { return x > 0.f ? x : ALPHA_ * x; }
__device__ __forceinline__ float eluf(float x)  { return x > 0.f ? x : expf(x) - 1.f; }
// 16B load at 4B alignment (safe form)
__device__ __forceinline__ float4 ld4u(const float* p) {
  float4 v;
  __builtin_memcpy(&v, p, 16);
  return v;
}

// Transpose + split-bf16 a KxN fp32 matrix into [N][K] hi/lo bf16 planes.
__global__ void k_wsplit(const float* __restrict__ Wm, __bf16* __restrict__ th,
                         __bf16* __restrict__ tl, int K, int Ncol) {
  const int idx = blockIdx.x * 256 + threadIdx.x;
  if (idx >= K * Ncol) return;
  const int k = idx / Ncol, c = idx - k * Ncol;
  float v = Wm[idx];
  __bf16 hv = (__bf16)v;
  th[(size_t)c * K + k] = hv;
  tl[(size_t)c * K + k] = (__bf16)(v - (float)hv);
}

// K1 (MFMA): Wh[b,h,n,d] = sum_f A[b,n,f] * W[h,f,d] via split-bf16 MFMA.
// Block = 128 rows x 1 head, 512 thr / 8 waves. s/d epilogue from acc regs.
__global__ __launch_bounds__(512) void k1_mfma(
    const float* __restrict__ A, const float* __restrict__ W,
    const float* __restrict__ ahp, float* __restrict__ Wh,
    float* __restrict__ sb, float* __restrict__ db) {
  __shared__ __align__(16) __bf16 wth[64 * 168];
  __shared__ __align__(16) __bf16 wtl[64 * 168];
  const int tid = threadIdx.x;
  const int lane = tid & 63;
  const int wv = tid >> 6;
  const int h = blockIdx.y;
  const int m0 = blockIdx.x * 128;

  {
    const float* Wg = W + (size_t)h * F_ * ND_;
    const int d = tid >> 3;
    const int kq = tid & 7;
    for (int k = kq; k < 168; k += 8) {
      float v = (k < F_) ? Wg[k * ND_ + d] : 0.f;
      __bf16 hv = (__bf16)v;
      wth[d * 168 + k] = hv;
      wtl[d * 168 + k] = (__bf16)(v - (float)hv);
    }
  }
  __syncthreads();

  const int mrow = m0 + wv * 16 + (lane & 15);
  const float* Ap = A + (size_t)mrow * F_;
  f32x4 acc[4];
#pragma unroll
  for (int t = 0; t < 4; ++t) acc[t] = f32x4{0.f, 0.f, 0.f, 0.f};

#pragma unroll
  for (int ks = 0; ks < 5; ++ks) {
    const int kb = ks * 32 + (lane >> 4) * 8;
    float av[8];
    if (ks < 4) {
      float4 a0 = ld4u(Ap + kb);
      float4 a1 = ld4u(Ap + kb + 4);
      av[0] = a0.x; av[1] = a0.y; av[2] = a0.z; av[3] = a0.w;
      av[4] = a1.x; av[5] = a1.y; av[6] = a1.z; av[7] = a1.w;
    } else {
#pragma unroll
      for (int j = 0; j < 8; ++j)
        av[j] = (kb + j < F_) ? Ap[kb + j] : 0.f;
    }
    bf16x8 ah8, al8;
#pragma unroll
    for (int j = 0; j < 8; ++j) {
      float v = av[j];
      __bf16 hv = (__bf16)v;
      ah8[j] = hv;
      al8[j] = (__bf16)(v - (float)hv);
    }
#pragma unroll
    for (int ct = 0; ct < 4; ++ct) {
      const int d = ct * 16 + (lane & 15);
      bf16x8 bh8 = *reinterpret_cast<const bf16x8*>(&wth[d * 168 + kb]);
      bf16x8 bl8 = *reinterpret_cast<const bf16x8*>(&wtl[d * 168 + kb]);
      acc[ct] = __builtin_amdgcn_mfma_f32_16x16x32_bf16(al8, bh8, acc[ct], 0, 0, 0);
      acc[ct] = __builtin_amdgcn_mfma_f32_16x16x32_bf16(ah8, bl8, acc[ct], 0, 0, 0);
      acc[ct] = __builtin_amdgcn_mfma_f32_16x16x32_bf16(ah8, bh8, acc[ct], 0, 0, 0);
    }
  }

  const size_t bh = (size_t)blockIdx.x * H_ + h;
  float* Whb = Wh + bh * N_ * ND_;
  const int n0 = wv * 16 + (lane >> 4) * 4;
#pragma unroll
  for (int ct = 0; ct < 4; ++ct) {
    const int d = ct * 16 + (lane & 15);
#pragma unroll
    for (int r = 0; r < 4; ++r)
      Whb[(size_t)(n0 + r) * ND_ + d] = acc[ct][r];
  }

  {
    float a1v[4], a2v[4];
#pragma unroll
    for (int ct = 0; ct < 4; ++ct) {
      a1v[ct] = ahp[h * 2 * ND_ + ct * 16 + (lane & 15)];
      a2v[ct] = ahp[h * 2 * ND_ + ND_ + ct * 16 + (lane & 15)];
    }
#pragma unroll
    for (int r = 0; r < 4; ++r) {
      float sv = 0.f, dv = 0.f;
#pragma unroll
      for (int ct = 0; ct < 4; ++ct) {
        sv = fmaf(acc[ct][r], a1v[ct], sv);
        dv = fmaf(acc[ct][r], a2v[ct], dv);
      }
#pragma unroll
      for (int m = 1; m <= 8; m <<= 1) {
        sv += __shfl_xor(sv, m, 64);
        dv += __shfl_xor(dv, m, 64);
      }
      if ((lane & 15) == 0) {
        sb[bh * N_ + n0 + r] = sv;
        db[bh * N_ + n0 + r] = dv;
      }
    }
  }
}

// K2: masked softmax + h = elu(attn @ Wh) via MFMA. Barrier-free.
// Epilogue writes hb as split-bf16 pair (A-operand of gemm512_s).
__global__ __launch_bounds__(512) void k2_attn1(
    const float* __restrict__ Wh, const float* __restrict__ sb,
    const float* __restrict__ db, const int* __restrict__ adj,
    __bf16* __restrict__ hbh, __bf16* __restrict__ hbl) {
  __shared__ __align__(16) __bf16 ph[128 * 136];
  __shared__ __align__(16) __bf16 pl[128 * 136];
  const int tid = threadIdx.x;
  const int lane = tid & 63;
  const int w = tid >> 6;
  const int bh = blockIdx.x;
  const int b = bh >> 3, h = bh & 7;
  const int i0 = w * 16;

  {
    const float dv0 = db[(size_t)bh * N_ + lane];
    const float dv1 = db[(size_t)bh * N_ + 64 + lane];
    int a0v[16], a1v[16];
#pragma unroll
    for (int r = 0; r < 16; ++r) {
      const int* arow = adj + ((size_t)b * N_ + i0 + r) * N_;
      a0v[r] = arow[lane];
      a1v[r] = arow[64 + lane];
    }
#pragma unroll
    for (int r = 0; r < 16; ++r) {
      const int i = i0 + r;
      const float sv = sb[(size_t)bh * N_ + i];
      float e0 = a0v[r] > 0 ? lrelu(sv + dv0) : NEG_;
      float e1 = a1v[r] > 0 ? lrelu(sv + dv1) : NEG_;
      float mx = wred_max(fmaxf(e0, e1));
      float x0 = expf(e0 - mx), x1 = expf(e1 - mx);
      float inv = 1.f / wred_sum(x0 + x1);
      float p0 = x0 * inv, p1 = x1 * inv;
      __bf16 h0 = (__bf16)p0, h1 = (__bf16)p1;
      ph[i * 136 + lane] = h0;
      ph[i * 136 + 64 + lane] = h1;
      pl[i * 136 + lane] = (__bf16)(p0 - (float)h0);
      pl[i * 136 + 64 + lane] = (__bf16)(p1 - (float)h1);
    }
  }
  // No __syncthreads: wave reads only rows it wrote.

  {
    const int arow = i0 + (lane & 15);
    const float* Whp = Wh + (size_t)bh * N_ * ND_;
    f32x4 acc[4];
#pragma unroll
    for (int t = 0; t < 4; ++t) acc[t] = f32x4{0.f, 0.f, 0.f, 0.f};
#pragma unroll
    for (int ks = 0; ks < 4; ++ks) {
      const int kb = ks * 32 + (lane >> 4) * 8;
      bf16x8 ah8 = *reinterpret_cast<const bf16x8*>(&ph[arow * 136 + kb]);
      bf16x8 al8 = *reinterpret_cast<const bf16x8*>(&pl[arow * 136 + kb]);
#pragma unroll
      for (int ct = 0; ct < 4; ++ct) {
        const int d = ct * 16 + (lane & 15);
        const float* Bc = Whp + (size_t)kb * ND_ + d;
        float bv[8];
#pragma unroll
        for (int i = 0; i < 8; ++i) bv[i] = Bc[(size_t)i * ND_];
        bf16x8 bh8, bl8;
#pragma unroll
        for (int j = 0; j < 8; ++j) {
          float v = bv[j];
          __bf16 hv = (__bf16)v;
          bh8[j] = hv;
          bl8[j] = (__bf16)(v - (float)hv);
        }
        acc[ct] = __builtin_amdgcn_mfma_f32_16x16x32_bf16(al8, bh8, acc[ct], 0, 0, 0);
        acc[ct] = __builtin_amdgcn_mfma_f32_16x16x32_bf16(ah8, bl8, acc[ct], 0, 0, 0);
        acc[ct] = __builtin_amdgcn_mfma_f32_16x16x32_bf16(ah8, bh8, acc[ct], 0, 0, 0);
      }
    }
    const int orow0 = i0 + (lane >> 4) * 4;
#pragma unroll
    for (int ct = 0; ct < 4; ++ct) {
      const int d = ct * 16 + (lane & 15);
#pragma unroll
      for (int r = 0; r < 4; ++r) {
        const int i = orow0 + r;
        float ev = eluf(acc[ct][r]);
        __bf16 hv = (__bf16)ev;
        const size_t idx = ((size_t)b * N_ + i) * (H_ * ND_) + h * ND_ + d;
        hbh[idx] = hv;
        hbl[idx] = (__bf16)(ev - (float)hv);
      }
    }
  }
}

// GEMM512: Wh2 = hb @ Wout via pre-split bf16 operands (MFMA).
// ALL B fragments of a k-step are loaded into static register arrays BEFORE
// any MFMA (forces ~22 outstanding loads -> one latency exposure per k-step
// instead of 22 serialized round-trips; fixes round-13 regression).
// Epilogue: Wh2 as transposed split pair + fused s2/d2.
__global__ __launch_bounds__(256) void gemm512_s(
    const __bf16* __restrict__ Ah, const __bf16* __restrict__ Al,
    const __bf16* __restrict__ BTh, const __bf16* __restrict__ BTl,
    const float* __restrict__ ao,
    __bf16* __restrict__ CTh, __bf16* __restrict__ CTl,
    float* __restrict__ s2, float* __restrict__ d2) {
  __shared__ float sdp[2][2][16][2];
  const int tid = threadIdx.x;
  const int lane = tid & 63;
  const int wv = tid >> 6;
  const int rs = wv >> 1, ch = wv & 1;
  const int m0 = blockIdx.x * 32 + rs * 16;
  const int ct0 = ch * 10;
  const int nct = ch ? 9 : 10;
  const int row = m0 + (lane & 15);
  f32x4 acc[10];
#pragma unroll
  for (int t = 0; t < 10; ++t) acc[t] = f32x4{0.f, 0.f, 0.f, 0.f};

  for (int ks = 0; ks < 16; ++ks) {
    const int kb = ks * 32 + (lane >> 4) * 8;
    bf16x8 ah8 = *reinterpret_cast<const bf16x8*>(Ah + (size_t)row * 512 + kb);
    bf16x8 al8 = *reinterpret_cast<const bf16x8*>(Al + (size_t)row * 512 + kb);
    bf16x8 bhv[10], blv[10];
#pragma unroll
    for (int t = 0; t < 10; ++t) {
      const int col = (ct0 + t) * 16 + (lane & 15);
      if (t < nct && col < HID_) {
        bhv[t] = *reinterpret_cast<const bf16x8*>(BTh + (size_t)col * 512 + kb);
        blv[t] = *reinterpret_cast<const bf16x8*>(BTl + (size_t)col * 512 + kb);
      } else {
        bhv[t] = bf16x8{0,0,0,0,0,0,0,0};
        blv[t] = bf16x8{0,0,0,0,0,0,0,0};
      }
    }
#pragma unroll
    for (int t = 0; t < 10; ++t) {
      if (t < nct) {
        acc[t] = __builtin_amdgcn_mfma_f32_16x16x32_bf16(al8, bhv[t], acc[t], 0, 0, 0);
        acc[t] = __builtin_amdgcn_mfma_f32_16x16x32_bf16(ah8, blv[t], acc[t], 0, 0, 0);
        acc[t] = __builtin_amdgcn_mfma_f32_16x16x32_bf16(ah8, bhv[t], acc[t], 0, 0, 0);
      }
    }
  }

  // Wh2T store (split pair, [b][col][k]); 4 consecutive k per lane-tile.
  const int b = blockIdx.x >> 2;
  const int kloc0 = (m0 & 127) + (lane >> 4) * 4;
#pragma unroll
  for (int t = 0; t < 10; ++t) {
    if (t < nct) {
      const int col = (ct0 + t) * 16 + (lane & 15);
      if (col < HID_) {
        bf16x4 hv4, lv4;
#pragma unroll
        for (int r = 0; r < 4; ++r) {
          float v = acc[t][r];
          __bf16 hv = (__bf16)v;
          hv4[r] = hv;
          lv4[r] = (__bf16)(v - (float)hv);
        }
        const size_t off = ((size_t)b * HID_ + col) * 128 + kloc0;
        *reinterpret_cast<bf16x4*>(CTh + off) = hv4;
        *reinterpret_cast<bf16x4*>(CTl + off) = lv4;
      }
    }
  }

  // Fused s2/d2 projections.
  {
    float aov[10], aod[10];
#pragma unroll
    for (int t = 0; t < 10; ++t) {
      const int col = (ct0 + t) * 16 + (lane & 15);
      const bool cv = (t < nct) && (col < HID_);
      aov[t] = cv ? ao[col] : 0.f;
      aod[t] = cv ? ao[HID_ + col] : 0.f;
    }
#pragma unroll
    for (int r = 0; r < 4; ++r) {
      float sv = 0.f, dv = 0.f;
#pragma unroll
      for (int t = 0; t < 10; ++t) {
        sv = fmaf(acc[t][r], aov[t], sv);
        dv = fmaf(acc[t][r], aod[t], dv);
      }
#pragma unroll
      for (int m = 1; m <= 8; m <<= 1) {
        sv += __shfl_xor(sv, m, 64);
        dv += __shfl_xor(dv, m, 64);
      }
      if ((lane & 15) == 0) {
        const int rl = (lane >> 4) * 4 + r;
        sdp[rs][ch][rl][0] = sv;
        sdp[rs][ch][rl][1] = dv;
      }
    }
  }
  __syncthreads();
  if (tid < 32) {
    const int rs2 = tid >> 4, rl = tid & 15;
    const int row2 = blockIdx.x * 32 + rs2 * 16 + rl;
    s2[row2] = sdp[rs2][0][rl][0] + sdp[rs2][1][rl][0];
    d2[row2] = sdp[rs2][0][rl][1] + sdp[rs2][1][rl][1];
  }
}

// GEMM128: ob = elu(p2 @ Wh2) via pre-split operands, batched B.
// Same batched-load structure as gemm512_s.
__global__ __launch_bounds__(256) void gemm128_s(
    const __bf16* __restrict__ Ah, const __bf16* __restrict__ Al,
    const __bf16* __restrict__ BTh, const __bf16* __restrict__ BTl,
    float* __restrict__ C) {
  const int tid = threadIdx.x;
  const int lane = tid & 63;
  const int wv = tid >> 6;
  const int rs = wv >> 1, ch = wv & 1;
  const int m0 = blockIdx.x * 32 + rs * 16;
  const int ct0 = ch * 10;
  const int nct = ch ? 9 : 10;
  const int row = m0 + (lane & 15);
  const int b = blockIdx.x >> 2;
  const __bf16* Bh = BTh + (size_t)b * HID_ * 128;
  const __bf16* Bl = BTl + (size_t)b * HID_ * 128;
  f32x4 acc[10];
#pragma unroll
  for (int t = 0; t < 10; ++t) acc[t] = f32x4{0.f, 0.f, 0.f, 0.f};

#pragma unroll
  for (int ks = 0; ks < 4; ++ks) {
    const int kb = ks * 32 + (lane >> 4) * 8;
    bf16x8 ah8 = *reinterpret_cast<const bf16x8*>(Ah + (size_t)row * 128 + kb);
    bf16x8 al8 = *reinterpret_cast<const bf16x8*>(Al + (size_t)row * 128 + kb);
    bf16x8 bhv[10], blv[10];
#pragma unroll
    for (int t = 0; t < 10; ++t) {
      const int col = (ct0 + t) * 16 + (lane & 15);
      if (t < nct && col < HID_) {
        bhv[t] = *reinterpret_cast<const bf16x8*>(Bh + (size_t)col * 128 + kb);
        blv[t] = *reinterpret_cast<const bf16x8*>(Bl + (size_t)col * 128 + kb);
      } else {
        bhv[t] = bf16x8{0,0,0,0,0,0,0,0};
        blv[t] = bf16x8{0,0,0,0,0,0,0,0};
      }
    }
#pragma unroll
    for (int t = 0; t < 10; ++t) {
      if (t < nct) {
        acc[t] = __builtin_amdgcn_mfma_f32_16x16x32_bf16(al8, bhv[t], acc[t], 0, 0, 0);
        acc[t] = __builtin_amdgcn_mfma_f32_16x16x32_bf16(ah8, blv[t], acc[t], 0, 0, 0);
        acc[t] = __builtin_amdgcn_mfma_f32_16x16x32_bf16(ah8, bhv[t], acc[t], 0, 0, 0);
      }
    }
  }

  const int orow = m0 + (lane >> 4) * 4;
#pragma unroll
  for (int t = 0; t < 10; ++t) {
    if (t < nct) {
      const int col = (ct0 + t) * 16 + (lane & 15);
      if (col < HID_) {
#pragma unroll
        for (int r = 0; r < 4; ++r)
          C[(size_t)(orow + r) * HID_ + col] = eluf(acc[t][r]);
      }
    }
  }
}

// Split-K partial GEMM for small-M matmuls: grid (M/ROWS, KSPLIT).
template <int ROWS, int KSPLIT>
__global__ void gemm_skp(const float* __restrict__ A, const float* __restrict__ Bm,
                         float* __restrict__ P, int M, int K, int N) {
  const int c = threadIdx.x;
  const int r0 = blockIdx.x * ROWS;
  const int ks = blockIdx.y;
  if (c >= N) return;
  const int kchunk = (K + KSPLIT - 1) / KSPLIT;
  const int k0 = ks * kchunk;
  const int k1 = (k0 + kchunk < K) ? (k0 + kchunk) : K;
  float acc[ROWS];
#pragma unroll
  for (int r = 0; r < ROWS; ++r) acc[r] = 0.f;
  int k = k0;
  for (; k + 3 < k1; k += 4) {
    const float b0 = Bm[(size_t)(k + 0) * N + c];
    const float b1 = Bm[(size_t)(k + 1) * N + c];
    const float b2 = Bm[(size_t)(k + 2) * N + c];
    const float b3 = Bm[(size_t)(k + 3) * N + c];
#pragma unroll
    for (int r = 0; r < ROWS; ++r) {
      float4 a = ld4u(A + (size_t)(r0 + r) * K + k);
      acc[r] = fmaf(a.x, b0, acc[r]);
      acc[r] = fmaf(a.y, b1, acc[r]);
      acc[r] = fmaf(a.z, b2, acc[r]);
      acc[r] = fmaf(a.w, b3, acc[r]);
    }
  }
  for (; k < k1; ++k) {
    const float bv = Bm[(size_t)k * N + c];
#pragma unroll
    for (int r = 0; r < ROWS; ++r)
      acc[r] = fmaf(A[(size_t)(r0 + r) * K + k], bv, acc[r]);
  }
#pragma unroll
  for (int r = 0; r < ROWS; ++r)
    P[((size_t)ks * M + r0 + r) * N + c] = acc[r];
}

// Reduce split-K partials + bias + act. act: 0 none, 1 relu.
template <int KSPLIT>
__global__ void k_red(const float* __restrict__ P, const float* __restrict__ bias,
                      float* __restrict__ C, int M, int N, int ldc, int act) {
  const int idx = blockIdx.x * 256 + threadIdx.x;
  if (idx >= M * N) return;
  const int m = idx / N, c = idx - m * N;
  float v = 0.f;
#pragma unroll
  for (int p = 0; p < KSPLIT; ++p) v += P[(size_t)p * M * N + idx];
  if (bias) v += bias[c];
  if (act == 1) v = fmaxf(v, 0.f);
  C[(size_t)m * ldc + c] = v;
}

// K5: attn2 probabilities p2 (split-bf16 pair). One wave per row i.
__global__ __launch_bounds__(256) void k5_p2(
    const float* __restrict__ s2, const float* __restrict__ d2,
    const int* __restrict__ adj, __bf16* __restrict__ p2h,
    __bf16* __restrict__ p2l) {
  const int lane = threadIdx.x & 63;
  const int row = blockIdx.x * 4 + (threadIdx.x >> 6);  // b*N+i
  const int b = row >> 7;
  float sv = s2[row];
  const float* drow = d2 + (size_t)b * N_;
  const int* arow = adj + (size_t)row * N_;
  float dv0 = drow[lane], dv1 = drow[64 + lane];
  int a0 = arow[lane], a1i = arow[64 + lane];
  float e0 = a0 > 0 ? lrelu(sv + dv0) : NEG_;
  float e1 = a1i > 0 ? lrelu(sv + dv1) : NEG_;
  float mx = wred_max(fmaxf(e0, e1));
  float x0 = expf(e0 - mx), x1 = expf(e1 - mx);
  float inv = 1.f / wred_sum(x0 + x1);
  float p0 = x0 * inv, p1 = x1 * inv;
  __bf16 h0 = (__bf16)p0, h1 = (__bf16)p1;
  p2h[(size_t)row * N_ + lane] = h0;
  p2l[(size_t)row * N_ + lane] = (__bf16)(p0 - (float)h0);
  p2h[(size_t)row * N_ + 64 + lane] = h1;
  p2l[(size_t)row * N_ + 64 + lane] = (__bf16)(p1 - (float)h1);
}

// K7: per-row max and log-sum-exp over 300 cols. One wave per row.
__global__ __launch_bounds__(256) void k7_lse(
    const float* __restrict__ ob, float* __restrict__ mx, float* __restrict__ ls) {
  const int lane = threadIdx.x & 63;
  const int row = blockIdx.x * 4 + (threadIdx.x >> 6);
  const float* orow = ob + (size_t)row * HID_;
  float v[5], m = -1e30f;
#pragma unroll
  for (int q = 0; q < 5; ++q) {
    int c = lane + q * 64;
    v[q] = (c < HID_) ? orow[c] : -1e30f;
    m = fmaxf(m, v[q]);
  }
  m = wred_max(m);
  float s = 0.f;
#pragma unroll
  for (int q = 0; q < 5; ++q) {
    int c = lane + q * 64;
    if (c < HID_) s += expf(v[q] - m);
  }
  s = wred_sum(s);
  if (lane == 0) { mx[row] = m; ls[row] = logf(s); }
}

// K8: gat_out[b,c] = mean_i (ob[b,i,c] - mx - ls). grid 256, block 320.
__global__ void k8_mean(const float* __restrict__ ob, const float* __restrict__ mx,
                        const float* __restrict__ ls, float* __restrict__ gat) {
  const int c = threadIdx.x;
  const int b = blockIdx.x;
  if (c >= HID_) return;
  float acc = 0.f;
  for (int i = 0; i < N_; ++i) {
    int row = b * N_ + i;
    acc += ob[(size_t)row * HID_ + c] - mx[row] - ls[row];
  }
  gat[(size_t)b * HID_ + c] = acc * (1.f / N_);
}

// out[b] = sigmoid(y[b,:] @ ffn_w2 + b2). One wave per row.
__global__ __launch_bounds__(256) void k_final(
    const float* __restrict__ y, const float* __restrict__ w2,
    const float* __restrict__ b2, float* __restrict__ out) {
  const int lane = threadIdx.x & 63;
  const int b = blockIdx.x * 4 + (threadIdx.x >> 6);
  float acc = 0.f;
  for (int c = lane; c < HID_; c += 64)
    acc = fmaf(y[(size_t)b * HID_ + c], w2[c], acc);
  acc = wred_sum(acc);
  if (lane == 0) out[b] = 1.f / (1.f + expf(-(acc + b2[0])));
}

extern "C" void kernel_launch(void* const* d_in, const int* in_sizes, int n_in,
                              void* d_out, int out_size, void* d_ws, size_t ws_size,
                              hipStream_t stream) {
  const float* atom  = (const float*)d_in[0];
  const float* fp    = (const float*)d_in[1];
  const float* Whead = (const float*)d_in[2];
  const float* ah    = (const float*)d_in[3];
  const float* Wout  = (const float*)d_in[4];
  const float* aout  = (const float*)d_in[5];
  const float* fc1w  = (const float*)d_in[6];
  const float* fc1b  = (const float*)d_in[7];
  const float* fc2w  = (const float*)d_in[8];
  const float* fc2b  = (const float*)d_in[9];
  const float* fgw   = (const float*)d_in[10];
  const float* fgb   = (const float*)d_in[11];
  const float* ffw   = (const float*)d_in[12];
  const float* ffb   = (const float*)d_in[13];
  const float* w1    = (const float*)d_in[14];
  const float* b1    = (const float*)d_in[15];
  const float* w2    = (const float*)d_in[16];
  const float* b2    = (const float*)d_in[17];
  const int*   adj   = (const int*)d_in[18];
  float* out = (float*)d_out;

  float* ws = (float*)d_ws;
  // Aliased layout (peak ~138.9 MB, unchanged):
  float* Wh     = ws;                      // 16,777,216 f  [k1 w, k2 r]
  __bf16* Wh2Th = (__bf16*)ws;             // 9.83M u16     [gemm512 w, gemm128 r]
  __bf16* Wh2Tl = (__bf16*)(ws + 4915200);
  float* pbuf   = ws;                      // [FPN + head phases only]
  __bf16* p2h   = (__bf16*)(ws + 9830400); // 4.19M u16 each
  __bf16* p2l   = (__bf16*)(ws + 11927552);
  float* sb     = ws + 16777216;
  float* db     = ws + 17039360;
  __bf16* hbh   = (__bf16*)(ws + 17301504); // 16.7M u16 each
  __bf16* hbl   = (__bf16*)(ws + 25690112);
  float* ob     = ws + 17301504;           // [gemm128 w; hb pair dead]
  float* s2     = ws + 34078720;
  float* d2     = s2 + 32768;
  float* mxb    = d2 + 32768;
  float* lsb    = mxb + 32768;
  float* gat    = lsb + 32768;             //  76,800
  float* fpn1   = gat + 76800;             // 131,072
  float* fpn2   = fpn1 + 131072;           //  76,800
  float* xcat   = fpn2 + 76800;            // 153,600
  float* yb     = xcat + 153600;           //  76,800
  __bf16* WoutTh = (__bf16*)xcat;          // WoutT pair borrows xcat slot
  __bf16* WoutTl = (__bf16*)(xcat + 76800);//  (dead before head phase)

  // Wout -> transposed split pair (B-operand of gemm512_s).
  k_wsplit<<<600, 256, 0, stream>>>(Wout, WoutTh, WoutTl, FP2_, HID_);

  // FPN branch (pbuf aliases Wh region; runs before k1)
  gemm_skp<4, 8><<<dim3(64, 8), 512, 0, stream>>>(fp, fc1w, pbuf, B_, FPD_, FP2_);
  k_red<8><<<512, 256, 0, stream>>>(pbuf, fc1b, fpn1, B_, FP2_, FP2_, 1);
  gemm_skp<4, 4><<<dim3(64, 4), 320, 0, stream>>>(fpn1, fc2w, pbuf, B_, FP2_, HID_);
  k_red<4><<<300, 256, 0, stream>>>(pbuf, fc2b, fpn2, B_, HID_, HID_, 0);

  // GAT stage 1
  k1_mfma<<<dim3(256, 8), 512, 0, stream>>>(atom, Whead, ah, Wh, sb, db);
  k2_attn1<<<2048, 512, 0, stream>>>(Wh, sb, db, adj, hbh, hbl);

  // Wh2 = hb @ Wout (+fused s2/d2), output transposed split pair.
  gemm512_s<<<1024, 256, 0, stream>>>(hbh, hbl, WoutTh, WoutTl, aout,
                                      Wh2Th, Wh2Tl, s2, d2);

  // GAT stage 2
  k5_p2<<<8192, 256, 0, stream>>>(s2, d2, adj, p2h, p2l);
  gemm128_s<<<1024, 256, 0, stream>>>(p2h, p2l, Wh2Th, Wh2Tl, ob);
  k7_lse<<<8192, 256, 0, stream>>>(ob, mxb, lsb);
  k8_mean<<<256, 320, 0, stream>>>(ob, mxb, lsb, gat);

  // Head (low ws region dead -> pbuf reuse safe; xcat written after WoutT dead)
  gemm_skp<4, 4><<<dim3(64, 4), 320, 0, stream>>>(gat, fgw, pbuf, B_, HID_, HID_);
  k_red<4><<<300, 256, 0, stream>>>(pbuf, fgb, xcat, B_, HID_, 2 * HID_, 1);
  gemm_skp<4, 4><<<dim3(64, 4), 320, 0, stream>>>(fpn2, ffw, pbuf, B_, HID_, HID_);
  k_red<4><<<300, 256, 0, stream>>>(pbuf, ffb, xcat + 300, B_, HID_, 2 * HID_, 1);
  gemm_skp<4, 4><<<dim3(64, 4), 320, 0, stream>>>(xcat, w1, pbuf, B_, 2 * HID_, HID_);
  k_red<4><<<300, 256, 0, stream>>>(pbuf, b1, yb, B_, HID_, HID_, 1);
  k_final<<<64, 256, 0, stream>>>(yb, w2, b2, out);
}

// Round 17
// 318.202 us; speedup vs baseline: 1.4902x; 1.3641x over previous
//
#include <hip/hip_runtime.h>
#include <math.h>

// Problem constants
#define B_    256
#define N_    128
#define F_    133
#define H_    8
#define ND_   64     // NHID
#define HID_  300
#define FPD_  1489
#define FP2_  512
#define ALPHA_ 0.2f
#define NEG_  -9.0e15f

typedef __bf16 bf16x8 __attribute__((ext_vector_type(8)));
typedef __bf16 bf16x4 __attribute__((ext_vector_type(4)));
typedef float f32x4 __attribute__((ext_vector_type(4)));

__device__ __forceinline__ float wred_sum(float v) {
#pragma unroll
  for (int m = 32; m >= 1; m >>= 1) v += __shfl_xor(v, m, 64);
  return v;
}
__device__ __forceinline__ float wred_max(float v) {
#pragma unroll
  for (int m = 32; m >= 1; m >>= 1) v = fmaxf(v, __shfl_xor(v, m, 64));
  return v;
}
__device__ __forceinline__ float lrelu(float x) { return x > 0.f ? x : ALPHA_ * x; }
__device__ __forceinline__ float eluf(float x)  { return x > 0.f ? x : expf(x) - 1.f; }
// 16B load at 4B alignment (safe form)
__device__ __forceinline__ float4 ld4u(const float* p) {
  float4 v;
  __builtin_memcpy(&v, p, 16);
  return v;
}

// Transpose + split-bf16 a KxN fp32 matrix into [N][K] hi/lo bf16 planes.
__global__ void k_wsplit(const float* __restrict__ Wm, __bf16* __restrict__ th,
                         __bf16* __restrict__ tl, int K, int Ncol) {
  const int idx = blockIdx.x * 256 + threadIdx.x;
  if (idx >= K * Ncol) return;
  const int k = idx / Ncol, c = idx - k * Ncol;
  float v = Wm[idx];
  __bf16 hv = (__bf16)v;
  th[(size_t)c * K + k] = hv;
  tl[(size_t)c * K + k] = (__bf16)(v - (float)hv);
}

// K1 (MFMA): Wh[b,h,n,d] = sum_f A[b,n,f] * W[h,f,d] via split-bf16 MFMA.
__global__ __launch_bounds__(512) void k1_mfma(
    const float* __restrict__ A, const float* __restrict__ W,
    const float* __restrict__ ahp, float* __restrict__ Wh,
    float* __restrict__ sb, float* __restrict__ db) {
  __shared__ __align__(16) __bf16 wth[64 * 168];
  __shared__ __align__(16) __bf16 wtl[64 * 168];
  const int tid = threadIdx.x;
  const int lane = tid & 63;
  const int wv = tid >> 6;
  const int h = blockIdx.y;
  const int m0 = blockIdx.x * 128;

  {
    const float* Wg = W + (size_t)h * F_ * ND_;
    const int d = tid >> 3;
    const int kq = tid & 7;
    for (int k = kq; k < 168; k += 8) {
      float v = (k < F_) ? Wg[k * ND_ + d] : 0.f;
      __bf16 hv = (__bf16)v;
      wth[d * 168 + k] = hv;
      wtl[d * 168 + k] = (__bf16)(v - (float)hv);
    }
  }
  __syncthreads();

  const int mrow = m0 + wv * 16 + (lane & 15);
  const float* Ap = A + (size_t)mrow * F_;
  f32x4 acc[4];
#pragma unroll
  for (int t = 0; t < 4; ++t) acc[t] = f32x4{0.f, 0.f, 0.f, 0.f};

#pragma unroll
  for (int ks = 0; ks < 5; ++ks) {
    const int kb = ks * 32 + (lane >> 4) * 8;
    float av[8];
    if (ks < 4) {
      float4 a0 = ld4u(Ap + kb);
      float4 a1 = ld4u(Ap + kb + 4);
      av[0] = a0.x; av[1] = a0.y; av[2] = a0.z; av[3] = a0.w;
      av[4] = a1.x; av[5] = a1.y; av[6] = a1.z; av[7] = a1.w;
    } else {
#pragma unroll
      for (int j = 0; j < 8; ++j)
        av[j] = (kb + j < F_) ? Ap[kb + j] : 0.f;
    }
    bf16x8 ah8, al8;
#pragma unroll
    for (int j = 0; j < 8; ++j) {
      float v = av[j];
      __bf16 hv = (__bf16)v;
      ah8[j] = hv;
      al8[j] = (__bf16)(v - (float)hv);
    }
#pragma unroll
    for (int ct = 0; ct < 4; ++ct) {
      const int d = ct * 16 + (lane & 15);
      bf16x8 bh8 = *reinterpret_cast<const bf16x8*>(&wth[d * 168 + kb]);
      bf16x8 bl8 = *reinterpret_cast<const bf16x8*>(&wtl[d * 168 + kb]);
      acc[ct] = __builtin_amdgcn_mfma_f32_16x16x32_bf16(al8, bh8, acc[ct], 0, 0, 0);
      acc[ct] = __builtin_amdgcn_mfma_f32_16x16x32_bf16(ah8, bl8, acc[ct], 0, 0, 0);
      acc[ct] = __builtin_amdgcn_mfma_f32_16x16x32_bf16(ah8, bh8, acc[ct], 0, 0, 0);
    }
  }

  const size_t bh = (size_t)blockIdx.x * H_ + h;
  float* Whb = Wh + bh * N_ * ND_;
  const int n0 = wv * 16 + (lane >> 4) * 4;
#pragma unroll
  for (int ct = 0; ct < 4; ++ct) {
    const int d = ct * 16 + (lane & 15);
#pragma unroll
    for (int r = 0; r < 4; ++r)
      Whb[(size_t)(n0 + r) * ND_ + d] = acc[ct][r];
  }

  {
    float a1v[4], a2v[4];
#pragma unroll
    for (int ct = 0; ct < 4; ++ct) {
      a1v[ct] = ahp[h * 2 * ND_ + ct * 16 + (lane & 15)];
      a2v[ct] = ahp[h * 2 * ND_ + ND_ + ct * 16 + (lane & 15)];
    }
#pragma unroll
    for (int r = 0; r < 4; ++r) {
      float sv = 0.f, dv = 0.f;
#pragma unroll
      for (int ct = 0; ct < 4; ++ct) {
        sv = fmaf(acc[ct][r], a1v[ct], sv);
        dv = fmaf(acc[ct][r], a2v[ct], dv);
      }
#pragma unroll
      for (int m = 1; m <= 8; m <<= 1) {
        sv += __shfl_xor(sv, m, 64);
        dv += __shfl_xor(dv, m, 64);
      }
      if ((lane & 15) == 0) {
        sb[bh * N_ + n0 + r] = sv;
        db[bh * N_ + n0 + r] = dv;
      }
    }
  }
}

// K2: masked softmax + h = elu(attn @ Wh) via MFMA. Barrier-free.
__global__ __launch_bounds__(512) void k2_attn1(
    const float* __restrict__ Wh, const float* __restrict__ sb,
    const float* __restrict__ db, const int* __restrict__ adj,
    __bf16* __restrict__ hbh, __bf16* __restrict__ hbl) {
  __shared__ __align__(16) __bf16 ph[128 * 136];
  __shared__ __align__(16) __bf16 pl[128 * 136];
  const int tid = threadIdx.x;
  const int lane = tid & 63;
  const int w = tid >> 6;
  const int bh = blockIdx.x;
  const int b = bh >> 3, h = bh & 7;
  const int i0 = w * 16;

  {
    const float dv0 = db[(size_t)bh * N_ + lane];
    const float dv1 = db[(size_t)bh * N_ + 64 + lane];
    int a0v[16], a1v[16];
#pragma unroll
    for (int r = 0; r < 16; ++r) {
      const int* arow = adj + ((size_t)b * N_ + i0 + r) * N_;
      a0v[r] = arow[lane];
      a1v[r] = arow[64 + lane];
    }
#pragma unroll
    for (int r = 0; r < 16; ++r) {
      const int i = i0 + r;
      const float sv = sb[(size_t)bh * N_ + i];
      float e0 = a0v[r] > 0 ? lrelu(sv + dv0) : NEG_;
      float e1 = a1v[r] > 0 ? lrelu(sv + dv1) : NEG_;
      float mx = wred_max(fmaxf(e0, e1));
      float x0 = expf(e0 - mx), x1 = expf(e1 - mx);
      float inv = 1.f / wred_sum(x0 + x1);
      float p0 = x0 * inv, p1 = x1 * inv;
      __bf16 h0 = (__bf16)p0, h1 = (__bf16)p1;
      ph[i * 136 + lane] = h0;
      ph[i * 136 + 64 + lane] = h1;
      pl[i * 136 + lane] = (__bf16)(p0 - (float)h0);
      pl[i * 136 + 64 + lane] = (__bf16)(p1 - (float)h1);
    }
  }
  // No __syncthreads: wave reads only rows it wrote.

  {
    const int arow = i0 + (lane & 15);
    const float* Whp = Wh + (size_t)bh * N_ * ND_;
    f32x4 acc[4];
#pragma unroll
    for (int t = 0; t < 4; ++t) acc[t] = f32x4{0.f, 0.f, 0.f, 0.f};
#pragma unroll
    for (int ks = 0; ks < 4; ++ks) {
      const int kb = ks * 32 + (lane >> 4) * 8;
      bf16x8 ah8 = *reinterpret_cast<const bf16x8*>(&ph[arow * 136 + kb]);
      bf16x8 al8 = *reinterpret_cast<const bf16x8*>(&pl[arow * 136 + kb]);
#pragma unroll
      for (int ct = 0; ct < 4; ++ct) {
        const int d = ct * 16 + (lane & 15);
        const float* Bc = Whp + (size_t)kb * ND_ + d;
        float bv[8];
#pragma unroll
        for (int i = 0; i < 8; ++i) bv[i] = Bc[(size_t)i * ND_];
        bf16x8 bh8, bl8;
#pragma unroll
        for (int j = 0; j < 8; ++j) {
          float v = bv[j];
          __bf16 hv = (__bf16)v;
          bh8[j] = hv;
          bl8[j] = (__bf16)(v - (float)hv);
        }
        acc[ct] = __builtin_amdgcn_mfma_f32_16x16x32_bf16(al8, bh8, acc[ct], 0, 0, 0);
        acc[ct] = __builtin_amdgcn_mfma_f32_16x16x32_bf16(ah8, bl8, acc[ct], 0, 0, 0);
        acc[ct] = __builtin_amdgcn_mfma_f32_16x16x32_bf16(ah8, bh8, acc[ct], 0, 0, 0);
      }
    }
    const int orow0 = i0 + (lane >> 4) * 4;
#pragma unroll
    for (int ct = 0; ct < 4; ++ct) {
      const int d = ct * 16 + (lane & 15);
#pragma unroll
      for (int r = 0; r < 4; ++r) {
        const int i = orow0 + r;
        float ev = eluf(acc[ct][r]);
        __bf16 hv = (__bf16)ev;
        const size_t idx = ((size_t)b * N_ + i) * (H_ * ND_) + h * ND_ + d;
        hbh[idx] = hv;
        hbl[idx] = (__bf16)(ev - (float)hv);
      }
    }
  }
}

// Double-buffered LDS GEMM on pre-split operands.
// Block = 64 rows (4 waves x 16) x one col-half (blockIdx.y: cols ch*160..).
// Per BK=32 chunk: issue next chunk's global loads -> ds_read B fragments +
// 30 MFMA -> ds_write next buffer -> barrier. B cols >=300 zero-filled.
// IS512: store Wh2 transposed split pair + s2/d2 per-half partials.
// else : store Cf = elu(acc) fp32, B batched per 128 rows.
template <int K, bool IS512>
__global__ __launch_bounds__(256) void gemm_lds(
    const __bf16* __restrict__ Ah, const __bf16* __restrict__ Al,
    const __bf16* __restrict__ BTh, const __bf16* __restrict__ BTl,
    const float* __restrict__ ao,
    __bf16* __restrict__ CTh, __bf16* __restrict__ CTl,
    float* __restrict__ s2p, float* __restrict__ d2p,
    float* __restrict__ Cf) {
  constexpr int NK = K / 32;
  __shared__ __align__(16) __bf16 lb[2][2][160 * 40];  // [buf][plane][col*40+k]
  const int tid = threadIdx.x;
  const int lane = tid & 63;
  const int w = tid >> 6;
  const int ch = blockIdx.y;
  const int colg0 = ch * 160;
  const int m0 = blockIdx.x * 64 + w * 16;
  const int row = m0 + (lane & 15);
  const int b = blockIdx.x >> 1;           // 64-row block -> batch (row/128)
  const __bf16* Bh_ = BTh + (IS512 ? (size_t)0 : (size_t)b * HID_ * K);
  const __bf16* Bl_ = BTl + (IS512 ? (size_t)0 : (size_t)b * HID_ * K);

  f32x4 acc[10];
#pragma unroll
  for (int t = 0; t < 10; ++t) acc[t] = f32x4{0.f, 0.f, 0.f, 0.f};

  bf16x8 sreg[5];

#define STAGE_LOAD(KS)                                                        \
  _Pragma("unroll") for (int r = 0; r < 5; ++r) {                             \
    const int un = r * 256 + tid;                                             \
    const int pl_ = un / 640, v_ = un % 640;                                  \
    const int col_ = v_ >> 2, kq_ = v_ & 3;                                   \
    const int colg_ = colg0 + col_;                                           \
    bf16x8 val = bf16x8{0, 0, 0, 0, 0, 0, 0, 0};                              \
    if (colg_ < HID_)                                                         \
      val = *reinterpret_cast<const bf16x8*>(                                 \
          (pl_ ? Bl_ : Bh_) + (size_t)colg_ * K + (KS) * 32 + kq_ * 8);       \
    sreg[r] = val;                                                            \
  }

#define STAGE_WRITE(BUF)                                                      \
  _Pragma("unroll") for (int r = 0; r < 5; ++r) {                             \
    const int un = r * 256 + tid;                                             \
    const int pl_ = un / 640, v_ = un % 640;                                  \
    const int col_ = v_ >> 2, kq_ = v_ & 3;                                   \
    *reinterpret_cast<bf16x8*>(&lb[(BUF)][pl_][col_ * 40 + kq_ * 8]) =        \
        sreg[r];                                                              \
  }

  int cur = 0;
  STAGE_LOAD(0)
  STAGE_WRITE(0)
  __syncthreads();

  for (int ks = 0; ks < NK; ++ks) {
    if (ks + 1 < NK) STAGE_LOAD(ks + 1)
    const int kb = ks * 32 + (lane >> 4) * 8;
    bf16x8 ah8 = *reinterpret_cast<const bf16x8*>(Ah + (size_t)row * K + kb);
    bf16x8 al8 = *reinterpret_cast<const bf16x8*>(Al + (size_t)row * K + kb);
#pragma unroll
    for (int t = 0; t < 10; ++t) {
      const int off = (t * 16 + (lane & 15)) * 40 + (lane >> 4) * 8;
      bf16x8 bh8 = *reinterpret_cast<const bf16x8*>(&lb[cur][0][off]);
      bf16x8 bl8 = *reinterpret_cast<const bf16x8*>(&lb[cur][1][off]);
      acc[t] = __builtin_amdgcn_mfma_f32_16x16x32_bf16(al8, bh8, acc[t], 0, 0, 0);
      acc[t] = __builtin_amdgcn_mfma_f32_16x16x32_bf16(ah8, bl8, acc[t], 0, 0, 0);
      acc[t] = __builtin_amdgcn_mfma_f32_16x16x32_bf16(ah8, bh8, acc[t], 0, 0, 0);
    }
    if (ks + 1 < NK) {
      STAGE_WRITE(cur ^ 1)
      __syncthreads();
    }
    cur ^= 1;
  }
#undef STAGE_LOAD
#undef STAGE_WRITE

  const int orow = m0 + (lane >> 4) * 4;
  if (IS512) {
    // Wh2T store ([b][col][128] split pair) — 4 consecutive k per lane-tile.
    const int kloc0 = orow & 127;
#pragma unroll
    for (int t = 0; t < 10; ++t) {
      const int colg = colg0 + t * 16 + (lane & 15);
      if (colg < HID_) {
        bf16x4 hv4, lv4;
#pragma unroll
        for (int r = 0; r < 4; ++r) {
          float v = acc[t][r];
          __bf16 hv = (__bf16)v;
          hv4[r] = hv;
          lv4[r] = (__bf16)(v - (float)hv);
        }
        const size_t off = ((size_t)b * HID_ + colg) * 128 + kloc0;
        *reinterpret_cast<bf16x4*>(CTh + off) = hv4;
        *reinterpret_cast<bf16x4*>(CTl + off) = lv4;
      }
    }
    // s2/d2 per-col-half partials (combined in k5).
    float aov[10], aod[10];
#pragma unroll
    for (int t = 0; t < 10; ++t) {
      const int colg = colg0 + t * 16 + (lane & 15);
      const bool cv = colg < HID_;
      aov[t] = cv ? ao[colg] : 0.f;
      aod[t] = cv ? ao[HID_ + colg] : 0.f;
    }
#pragma unroll
    for (int r = 0; r < 4; ++r) {
      float sv = 0.f, dv = 0.f;
#pragma unroll
      for (int t = 0; t < 10; ++t) {
        sv = fmaf(acc[t][r], aov[t], sv);
        dv = fmaf(acc[t][r], aod[t], dv);
      }
#pragma unroll
      for (int m = 1; m <= 8; m <<= 1) {
        sv += __shfl_xor(sv, m, 64);
        dv += __shfl_xor(dv, m, 64);
      }
      if ((lane & 15) == 0) {
        s2p[(size_t)ch * 32768 + orow + r] = sv;
        d2p[(size_t)ch * 32768 + orow + r] = dv;
      }
    }
  } else {
#pragma unroll
    for (int t = 0; t < 10; ++t) {
      const int colg = colg0 + t * 16 + (lane & 15);
      if (colg < HID_) {
#pragma unroll
        for (int r = 0; r < 4; ++r)
          Cf[(size_t)(orow + r) * HID_ + colg] = eluf(acc[t][r]);
      }
    }
  }
}

// Split-K partial GEMM for small-M matmuls: grid (M/ROWS, KSPLIT).
template <int ROWS, int KSPLIT>
__global__ void gemm_skp(const float* __restrict__ A, const float* __restrict__ Bm,
                         float* __restrict__ P, int M, int K, int N) {
  const int c = threadIdx.x;
  const int r0 = blockIdx.x * ROWS;
  const int ks = blockIdx.y;
  if (c >= N) return;
  const int kchunk = (K + KSPLIT - 1) / KSPLIT;
  const int k0 = ks * kchunk;
  const int k1 = (k0 + kchunk < K) ? (k0 + kchunk) : K;
  float acc[ROWS];
#pragma unroll
  for (int r = 0; r < ROWS; ++r) acc[r] = 0.f;
  int k = k0;
  for (; k + 3 < k1; k += 4) {
    const float b0 = Bm[(size_t)(k + 0) * N + c];
    const float b1 = Bm[(size_t)(k + 1) * N + c];
    const float b2 = Bm[(size_t)(k + 2) * N + c];
    const float b3 = Bm[(size_t)(k + 3) * N + c];
#pragma unroll
    for (int r = 0; r < ROWS; ++r) {
      float4 a = ld4u(A + (size_t)(r0 + r) * K + k);
      acc[r] = fmaf(a.x, b0, acc[r]);
      acc[r] = fmaf(a.y, b1, acc[r]);
      acc[r] = fmaf(a.z, b2, acc[r]);
      acc[r] = fmaf(a.w, b3, acc[r]);
    }
  }
  for (; k < k1; ++k) {
    const float bv = Bm[(size_t)k * N + c];
#pragma unroll
    for (int r = 0; r < ROWS; ++r)
      acc[r] = fmaf(A[(size_t)(r0 + r) * K + k], bv, acc[r]);
  }
#pragma unroll
  for (int r = 0; r < ROWS; ++r)
    P[((size_t)ks * M + r0 + r) * N + c] = acc[r];
}

// Reduce split-K partials + bias + act. act: 0 none, 1 relu.
template <int KSPLIT>
__global__ void k_red(const float* __restrict__ P, const float* __restrict__ bias,
                      float* __restrict__ C, int M, int N, int ldc, int act) {
  const int idx = blockIdx.x * 256 + threadIdx.x;
  if (idx >= M * N) return;
  const int m = idx / N, c = idx - m * N;
  float v = 0.f;
#pragma unroll
  for (int p = 0; p < KSPLIT; ++p) v += P[(size_t)p * M * N + idx];
  if (bias) v += bias[c];
  if (act == 1) v = fmaxf(v, 0.f);
  C[(size_t)m * ldc + c] = v;
}

// K5: attn2 probabilities p2 (split-bf16 pair); sums s2/d2 half-partials.
__global__ __launch_bounds__(256) void k5_p2(
    const float* __restrict__ s2p, const float* __restrict__ d2p,
    const int* __restrict__ adj, __bf16* __restrict__ p2h,
    __bf16* __restrict__ p2l) {
  const int lane = threadIdx.x & 63;
  const int row = blockIdx.x * 4 + (threadIdx.x >> 6);  // b*N+i
  const int b = row >> 7;
  float sv = s2p[row] + s2p[32768 + row];
  const float* d0 = d2p + (size_t)b * N_;
  const float* d1 = d2p + 32768 + (size_t)b * N_;
  const int* arow = adj + (size_t)row * N_;
  float dv0 = d0[lane] + d1[lane];
  float dv1 = d0[64 + lane] + d1[64 + lane];
  int a0 = arow[lane], a1i = arow[64 + lane];
  float e0 = a0 > 0 ? lrelu(sv + dv0) : NEG_;
  float e1 = a1i > 0 ? lrelu(sv + dv1) : NEG_;
  float mx = wred_max(fmaxf(e0, e1));
  float x0 = expf(e0 - mx), x1 = expf(e1 - mx);
  float inv = 1.f / wred_sum(x0 + x1);
  float p0 = x0 * inv, p1 = x1 * inv;
  __bf16 h0 = (__bf16)p0, h1 = (__bf16)p1;
  p2h[(size_t)row * N_ + lane] = h0;
  p2l[(size_t)row * N_ + lane] = (__bf16)(p0 - (float)h0);
  p2h[(size_t)row * N_ + 64 + lane] = h1;
  p2l[(size_t)row * N_ + 64 + lane] = (__bf16)(p1 - (float)h1);
}

// K7: per-row max and log-sum-exp over 300 cols. One wave per row.
__global__ __launch_bounds__(256) void k7_lse(
    const float* __restrict__ ob, float* __restrict__ mx, float* __restrict__ ls) {
  const int lane = threadIdx.x & 63;
  const int row = blockIdx.x * 4 + (threadIdx.x >> 6);
  const float* orow = ob + (size_t)row * HID_;
  float v[5], m = -1e30f;
#pragma unroll
  for (int q = 0; q < 5; ++q) {
    int c = lane + q * 64;
    v[q] = (c < HID_) ? orow[c] : -1e30f;
    m = fmaxf(m, v[q]);
  }
  m = wred_max(m);
  float s = 0.f;
#pragma unroll
  for (int q = 0; q < 5; ++q) {
    int c = lane + q * 64;
    if (c < HID_) s += expf(v[q] - m);
  }
  s = wred_sum(s);
  if (lane == 0) { mx[row] = m; ls[row] = logf(s); }
}

// K8: gat_out[b,c] = mean_i (ob[b,i,c] - mx - ls). grid 256, block 320.
__global__ void k8_mean(const float* __restrict__ ob, const float* __restrict__ mx,
                        const float* __restrict__ ls, float* __restrict__ gat) {
  const int c = threadIdx.x;
  const int b = blockIdx.x;
  if (c >= HID_) return;
  float acc = 0.f;
  for (int i = 0; i < N_; ++i) {
    int row = b * N_ + i;
    acc += ob[(size_t)row * HID_ + c] - mx[row] - ls[row];
  }
  gat[(size_t)b * HID_ + c] = acc * (1.f / N_);
}

// out[b] = sigmoid(y[b,:] @ ffn_w2 + b2). One wave per row.
__global__ __launch_bounds__(256) void k_final(
    const float* __restrict__ y, const float* __restrict__ w2,
    const float* __restrict__ b2, float* __restrict__ out) {
  const int lane = threadIdx.x & 63;
  const int b = blockIdx.x * 4 + (threadIdx.x >> 6);
  float acc = 0.f;
  for (int c = lane; c < HID_; c += 64)
    acc = fmaf(y[(size_t)b * HID_ + c], w2[c], acc);
  acc = wred_sum(acc);
  if (lane == 0) out[b] = 1.f / (1.f + expf(-(acc + b2[0])));
}

extern "C" void kernel_launch(void* const* d_in, const int* in_sizes, int n_in,
                              void* d_out, int out_size, void* d_ws, size_t ws_size,
                              hipStream_t stream) {
  const float* atom  = (const float*)d_in[0];
  const float* fp    = (const float*)d_in[1];
  const float* Whead = (const float*)d_in[2];
  const float* ah    = (const float*)d_in[3];
  const float* Wout  = (const float*)d_in[4];
  const float* aout  = (const float*)d_in[5];
  const float* fc1w  = (const float*)d_in[6];
  const float* fc1b  = (const float*)d_in[7];
  const float* fc2w  = (const float*)d_in[8];
  const float* fc2b  = (const float*)d_in[9];
  const float* fgw   = (const float*)d_in[10];
  const float* fgb   = (const float*)d_in[11];
  const float* ffw   = (const float*)d_in[12];
  const float* ffb   = (const float*)d_in[13];
  const float* w1    = (const float*)d_in[14];
  const float* b1    = (const float*)d_in[15];
  const float* w2    = (const float*)d_in[16];
  const float* b2    = (const float*)d_in[17];
  const int*   adj   = (const int*)d_in[18];
  float* out = (float*)d_out;

  float* ws = (float*)d_ws;
  // Aliased layout (peak ~138.6 MB, unchanged):
  float* Wh     = ws;                      // 16,777,216 f  [k1 w, k2 r]
  __bf16* Wh2Th = (__bf16*)ws;             // 9.83M u16     [gemm512 w, gemm128 r]
  __bf16* Wh2Tl = (__bf16*)(ws + 4915200);
  float* pbuf   = ws;                      // [FPN + head phases only]
  __bf16* p2h   = (__bf16*)(ws + 9830400); // 4.19M u16 each
  __bf16* p2l   = (__bf16*)(ws + 11927552);
  float* s2p    = ws + 14024704;           // [2][32768]  (free gap in p2 region)
  float* d2p    = ws + 14090240;           // [2][32768]
  float* sb     = ws + 16777216;
  float* db     = ws + 17039360;
  __bf16* hbh   = (__bf16*)(ws + 17301504); // 16.7M u16 each
  __bf16* hbl   = (__bf16*)(ws + 25690112);
  float* ob     = ws + 17301504;           // [gemm128 w; hb pair dead]
  float* mxb    = ws + 34078720 + 65536;
  float* lsb    = mxb + 32768;
  float* gat    = lsb + 32768;             //  76,800
  float* fpn1   = gat + 76800;             // 131,072
  float* fpn2   = fpn1 + 131072;           //  76,800
  float* xcat   = fpn2 + 76800;            // 153,600
  float* yb     = xcat + 153600;           //  76,800
  __bf16* WoutTh = (__bf16*)xcat;          // WoutT pair borrows xcat slot
  __bf16* WoutTl = (__bf16*)(xcat + 76800);//  (dead before head phase)

  // Wout -> transposed split pair (B-operand of gemm512).
  k_wsplit<<<600, 256, 0, stream>>>(Wout, WoutTh, WoutTl, FP2_, HID_);

  // FPN branch (pbuf aliases Wh region; runs before k1)
  gemm_skp<4, 8><<<dim3(64, 8), 512, 0, stream>>>(fp, fc1w, pbuf, B_, FPD_, FP2_);
  k_red<8><<<512, 256, 0, stream>>>(pbuf, fc1b, fpn1, B_, FP2_, FP2_, 1);
  gemm_skp<4, 4><<<dim3(64, 4), 320, 0, stream>>>(fpn1, fc2w, pbuf, B_, FP2_, HID_);
  k_red<4><<<300, 256, 0, stream>>>(pbuf, fc2b, fpn2, B_, HID_, HID_, 0);

  // GAT stage 1
  k1_mfma<<<dim3(256, 8), 512, 0, stream>>>(atom, Whead, ah, Wh, sb, db);
  k2_attn1<<<2048, 512, 0, stream>>>(Wh, sb, db, adj, hbh, hbl);

  // Wh2 = hb @ Wout (+fused s2/d2 partials), output transposed split pair.
  gemm_lds<512, true><<<dim3(512, 2), 256, 0, stream>>>(
      hbh, hbl, WoutTh, WoutTl, aout, Wh2Th, Wh2Tl, s2p, d2p, nullptr);

  // GAT stage 2
  k5_p2<<<8192, 256, 0, stream>>>(s2p, d2p, adj, p2h, p2l);
  gemm_lds<128, false><<<dim3(512, 2), 256, 0, stream>>>(
      p2h, p2l, Wh2Th, Wh2Tl, nullptr, nullptr, nullptr, nullptr, nullptr, ob);
  k7_lse<<<8192, 256, 0, stream>>>(ob, mxb, lsb);
  k8_mean<<<256, 320, 0, stream>>>(ob, mxb, lsb, gat);

  // Head (low ws region dead -> pbuf reuse safe; xcat written after WoutT dead)
  gemm_skp<4, 4><<<dim3(64, 4), 320, 0, stream>>>(gat, fgw, pbuf, B_, HID_, HID_);
  k_red<4><<<300, 256, 0, stream>>>(pbuf, fgb, xcat, B_, HID_, 2 * HID_, 1);
  gemm_skp<4, 4><<<dim3(64, 4), 320, 0, stream>>>(fpn2, ffw, pbuf, B_, HID_, HID_);
  k_red<4><<<300, 256, 0, stream>>>(pbuf, ffb, xcat + 300, B_, HID_, 2 * HID_, 1);
  gemm_skp<4, 4><<<dim3(64, 4), 320, 0, stream>>>(xcat, w1, pbuf, B_, 2 * HID_, HID_);
  k_red<4><<<300, 256, 0, stream>>>(pbuf, b1, yb, B_, HID_, HID_, 1);
  k_final<<<64, 256, 0, stream>>>(yb, w2, b2, out);
}